// Round 10
// baseline (122.357 us; speedup 1.0000x reference)
//
#include <hip/hip_runtime.h>
#include <hip/hip_bf16.h>

typedef _Float16 f16;
typedef f16 f16x8 __attribute__((ext_vector_type(8)));
typedef f16 f16x4 __attribute__((ext_vector_type(4)));
typedef float f32x4 __attribute__((ext_vector_type(4)));

#define MFMA_F16(a, b, c) __builtin_amdgcn_mfma_f32_16x16x32_f16((a), (b), (c), 0, 0, 0)
#define LOG2E 1.44269504f

// ---------------------------------------------------------------------------
// async global->LDS 16B copy
// ---------------------------------------------------------------------------
__device__ __forceinline__ void ld_lds16(const void* g, void* l) {
  __builtin_amdgcn_global_load_lds((const __attribute__((address_space(1))) void*)g,
                                   (__attribute__((address_space(3))) void*)l, 16, 0, 0);
}

// ---------------------------------------------------------------------------
// cast fp32 -> fp16; wq scaled by log2(e) (exp2-domain softmax)
// ---------------------------------------------------------------------------
__global__ __launch_bounds__(256) void cast_all(
    const float* __restrict__ hs, const float* __restrict__ wq,
    const float* __restrict__ wk, const float* __restrict__ wv,
    const float* __restrict__ wo, f16* __restrict__ hb,
    f16* __restrict__ wqb, f16* __restrict__ wkb,
    f16* __restrict__ wvb, f16* __restrict__ wob) {
  int idx = blockIdx.x * 256 + threadIdx.x;  // 1,572,864 float4 chunks total
  const float* src;
  f16* dst;
  int j;
  float scale = 1.0f;
  if (idx < 524288) {  // hidden: 2M floats / 4
    src = hs; dst = hb; j = idx;
  } else {
    int t = idx - 524288;
    int w = t >> 18;      // 262144 float4 per weight
    j = t & 262143;
    src = (w == 0) ? wq : (w == 1) ? wk : (w == 2) ? wv : wo;
    dst = (w == 0) ? wqb : (w == 1) ? wkb : (w == 2) ? wvb : wob;
    if (w == 0) scale = LOG2E;
  }
  float4 v = ((const float4*)src)[j];
  f16x4 o;
  o[0] = (f16)(v.x * scale); o[1] = (f16)(v.y * scale);
  o[2] = (f16)(v.z * scale); o[3] = (f16)(v.w * scale);
  ((f16x4*)dst)[j] = o;
}

// ---------------------------------------------------------------------------
// relative-position bias table: btab[h][rel + 2047], rel = kv - q, *log2(e)
// ---------------------------------------------------------------------------
__global__ __launch_bounds__(256) void build_bias(const float* __restrict__ rb,
                                                  float* __restrict__ btab) {
  int idx = blockIdx.x * 256 + threadIdx.x;  // 65536 = 16 heads * 4096
  int h = idx >> 12;
  int t = idx & 4095;
  int rel = t - 2047;
  int bucket = (rel > 0) ? 16 : 0;
  int a = (rel < 0) ? -rel : rel;
  int lg;
  if (a < 8) {
    lg = a;
  } else {
    int cnt = (a >= 12) + (a >= 16) + (a >= 23) + (a >= 32) + (a >= 46) +
              (a >= 64) + (a >= 91);
    lg = 8 + cnt;  // max 15
  }
  bucket += lg;
  btab[idx] = rb[bucket * 16 + h] * LOG2E;  // rel_bias[32][16]
}

// ---------------------------------------------------------------------------
// GEMM mainloop: C[64x128] tile of A[M,1024] * B[N,1024]^T, double-buffered:
// stage(k+64) issued BEFORE compute(k), one barrier per iter (r9 had
// stage->sync->compute, fully exposing L2 latency 16x).
// ---------------------------------------------------------------------------
__device__ __forceinline__ void gemm_mainloop(const f16* __restrict__ A,
                                              const f16* __restrict__ B,
                                              int brow, int bcol,
                                              f16 (*lA)[64 * 64],
                                              f16 (*lB)[128 * 64],
                                              f32x4 acc[4][2]) {
  const int tid = threadIdx.x;
  const int lane = tid & 63;
  const int wn = tid >> 6;
  const int lo = lane & 15;
  const int hi = lane >> 4;
  const int sw = lo & 7;
  const int sr = tid >> 3;                       // 0..31
  const int se = (((tid & 7) ^ (sr & 7)) << 3);  // swizzled col elem offset
  const f16* gA = A + (size_t)(brow + sr) * 1024 + se;
  const f16* gB = B + (size_t)(bcol + sr) * 1024 + se;

#define GSTAGE(bi, k0_)                                                        \
  do {                                                                         \
    ld_lds16(gA + (k0_),             lA[bi] + tid * 8);                        \
    ld_lds16(gA + (k0_) + 32 * 1024, lA[bi] + tid * 8 + 2048);                 \
    ld_lds16(gB + (k0_),             lB[bi] + tid * 8);                        \
    ld_lds16(gB + (k0_) + 32 * 1024, lB[bi] + tid * 8 + 2048);                 \
    ld_lds16(gB + (k0_) + 64 * 1024, lB[bi] + tid * 8 + 4096);                 \
    ld_lds16(gB + (k0_) + 96 * 1024, lB[bi] + tid * 8 + 6144);                 \
  } while (0)

  GSTAGE(0, 0);
  __syncthreads();
  for (int k0 = 0; k0 < 1024; k0 += 64) {
    const int bi = (k0 >> 6) & 1;
    if (k0 < 960) GSTAGE(bi ^ 1, k0 + 64);
    f16x8 af[4][2], bf[2][2];
#pragma unroll
    for (int m = 0; m < 4; ++m)
#pragma unroll
      for (int ks = 0; ks < 2; ++ks)
        af[m][ks] = *(const f16x8*)(lA[bi] + (m * 16 + lo) * 64 +
                                    (((ks << 2) | hi) ^ sw) * 8);
#pragma unroll
    for (int j = 0; j < 2; ++j)
#pragma unroll
      for (int ks = 0; ks < 2; ++ks)
        bf[j][ks] = *(const f16x8*)(lB[bi] + (wn * 32 + j * 16 + lo) * 64 +
                                    (((ks << 2) | hi) ^ sw) * 8);
    __builtin_amdgcn_s_setprio(1);
#pragma unroll
    for (int m = 0; m < 4; ++m)
#pragma unroll
      for (int j = 0; j < 2; ++j)
#pragma unroll
        for (int ks = 0; ks < 2; ++ks)
          acc[m][j] = MFMA_F16(af[m][ks], bf[j][ks], acc[m][j]);
    __builtin_amdgcn_s_setprio(0);
    __syncthreads();  // stage(bi^1) retired + everyone done reading bi
  }
#undef GSTAGE
}

// QKV projections fused over blockIdx.z (0=Q, 1=K, 2=V-transposed+pi-permuted)
__global__ __launch_bounds__(256) void gemm_qkv(
    const f16* __restrict__ A, const f16* __restrict__ Wq,
    const f16* __restrict__ Wk, const f16* __restrict__ Wv,
    f16* __restrict__ Qo, f16* __restrict__ Ko, f16* __restrict__ VTo) {
  __shared__ __align__(16) f16 lA[2][64 * 64];
  __shared__ __align__(16) f16 lB[2][128 * 64];
  const int z = blockIdx.z;
  const f16* B = (z == 0) ? Wq : (z == 1) ? Wk : Wv;
  const int brow = blockIdx.x * 64, bcol = blockIdx.y * 128;
  f32x4 acc[4][2];
#pragma unroll
  for (int m = 0; m < 4; ++m)
#pragma unroll
    for (int j = 0; j < 2; ++j) acc[m][j] = f32x4{0.f, 0.f, 0.f, 0.f};
  gemm_mainloop(A, B, brow, bcol, lA, lB, acc);
  const int lane = threadIdx.x & 63, wn = threadIdx.x >> 6;
  const int lo = lane & 15, hi = lane >> 4;
  if (z < 2) {
    f16* C = z ? Ko : Qo;
#pragma unroll
    for (int m = 0; m < 4; ++m)
#pragma unroll
      for (int j = 0; j < 2; ++j) {
        int col = bcol + wn * 32 + j * 16 + lo;
        int row0 = brow + m * 16 + hi * 4;
#pragma unroll
        for (int r = 0; r < 4; ++r)
          C[(size_t)(row0 + r) * 1024 + col] = (f16)acc[m][j][r];
      }
  } else {
    // V transposed: VT[n][s'], pi-permuted within each 64-kv block so a PV
    // fragment is one contiguous b128 in LDS.
#pragma unroll
    for (int m = 0; m < 4; ++m)
#pragma unroll
      for (int j = 0; j < 2; ++j) {
        int col = bcol + wn * 32 + j * 16 + lo;   // n
        int g = m * 4 + hi;
        int w = g & 7;
        int gp = (g & 8) | ((w < 4) ? (2 * w) : (2 * (w - 4) + 1));
        int sp = brow + gp * 4;                   // permuted s
        f16x4 v4;
#pragma unroll
        for (int r = 0; r < 4; ++r) v4[r] = (f16)acc[m][j][r];
        *(f16x4*)(VTo + (size_t)col * 2048 + sp) = v4;
      }
  }
}

// output projection: AO[2048,1024] * Wo[1024,1024]^T -> fp32 d_out
__global__ __launch_bounds__(256) void gemm_out(const f16* __restrict__ A,
                                                const f16* __restrict__ W,
                                                float* __restrict__ C) {
  __shared__ __align__(16) f16 lA[2][64 * 64];
  __shared__ __align__(16) f16 lB[2][128 * 64];
  const int brow = blockIdx.x * 64, bcol = blockIdx.y * 128;
  f32x4 acc[4][2];
#pragma unroll
  for (int m = 0; m < 4; ++m)
#pragma unroll
    for (int j = 0; j < 2; ++j) acc[m][j] = f32x4{0.f, 0.f, 0.f, 0.f};
  gemm_mainloop(A, W, brow, bcol, lA, lB, acc);
  const int lane = threadIdx.x & 63, wn = threadIdx.x >> 6;
  const int lo = lane & 15, hi = lane >> 4;
#pragma unroll
  for (int m = 0; m < 4; ++m)
#pragma unroll
    for (int j = 0; j < 2; ++j) {
      int col = bcol + wn * 32 + j * 16 + lo;
      int row0 = brow + m * 16 + hi * 4;
#pragma unroll
      for (int r = 0; r < 4; ++r)
        C[(size_t)(row0 + r) * 1024 + col] = acc[m][j][r];
    }
}

// ---------------------------------------------------------------------------
// Flash attention v10: r9 base (32q/wave, z-split, pi-permuted V, exp2,
// far-bias, defer-max) with 128-kv SLOTS: 2 tiles per barrier -> 8 slots,
// half the barrier/drain count, 16-MFMA QK^T cluster, softmax(t0) overlaps
// V reads / PV(t0) overlaps softmax(t1) inside one barrier region.
// ---------------------------------------------------------------------------
__global__ __launch_bounds__(256) void attn_kernel(
    const f16* __restrict__ Q, const f16* __restrict__ K,
    const f16* __restrict__ VT, const float* __restrict__ btab,
    f16* __restrict__ Oh, float2* __restrict__ Ml) {
  __shared__ __align__(16) f16 lK[2][8192];   // [128 kv][64 d]
  __shared__ __align__(16) f16 lV[2][8192];   // [64 dv][128 s']
  __shared__ __align__(16) float biasL[1152];

  const int h = blockIdx.y;
  const int q0 = blockIdx.x * 128;
  const int z = blockIdx.z;
  const int kvbase = z * 1024;
  const int tid = threadIdx.x;
  const int wave = tid >> 6, lane = tid & 63;
  const int lo = lane & 15, hi = lane >> 4;
  const int sw = lo & 7;
  const int qlo = q0 + wave * 32;
  const int myq0 = qlo + lo;
  const int myq1 = qlo + 16 + lo;

  const f16* Kh = K + h * 64;
  const f16* VTh = VT + (size_t)h * 64 * 2048;

  // Q fragments [qh][kk]
  f16x8 qf[2][2];
#pragma unroll
  for (int kk = 0; kk < 2; ++kk) {
    qf[0][kk] = *(const f16x8*)(Q + (size_t)myq0 * 1024 + h * 64 + kk * 32 + hi * 8);
    qf[1][kk] = *(const f16x8*)(Q + (size_t)myq1 * 1024 + h * 64 + kk * 32 + hi * 8);
  }
  const float bp = btab[h * 4096 + 4094];  // rel >= +91 (bucket 31)
  const float bn = btab[h * 4096 + 0];     // rel <= -91 (bucket 15)

  // bias window: idx = (kv - kvbase) + 127 - (q - q0), range [0, 1152)
  {
    const float* bsrc = btab + h * 4096 + 1920 + kvbase - q0;
    for (int c = tid; c < 288; c += 256)
      ld_lds16(bsrc + c * 4, biasL + c * 4);
  }
  const int bofs0 = 127 - wave * 32 - lo;
  const int bofs1 = bofs0 - 16;

  // staging: 1024 chunks each for K and V per 128-kv slot; 4 chunks/thread
  const int scA = tid, scB = 256 + tid, scC = 512 + tid, scD = 768 + tid;
  const int rkA = scA >> 3, ekA = (scA & 7) ^ (rkA & 7);
  const int rkB = scB >> 3, ekB = (scB & 7) ^ (rkB & 7);
  const int rkC = scC >> 3, ekC = (scC & 7) ^ (rkC & 7);
  const int rkD = scD >> 3, ekD = (scD & 7) ^ (rkD & 7);
  const int rvA = scA >> 4, evA = (scA & 15) ^ (rvA & 15);
  const int rvB = scB >> 4, evB = (scB & 15) ^ (rvB & 15);
  const int rvC = scC >> 4, evC = (scC & 15) ^ (rvC & 15);
  const int rvD = scD >> 4, evD = (scD & 15) ^ (rvD & 15);

#define STAGE128(bufi, kv)                                                     \
  do {                                                                         \
    ld_lds16(Kh + (size_t)((kv) + rkA) * 1024 + ekA * 8, &lK[bufi][scA * 8]);  \
    ld_lds16(Kh + (size_t)((kv) + rkB) * 1024 + ekB * 8, &lK[bufi][scB * 8]);  \
    ld_lds16(Kh + (size_t)((kv) + rkC) * 1024 + ekC * 8, &lK[bufi][scC * 8]);  \
    ld_lds16(Kh + (size_t)((kv) + rkD) * 1024 + ekD * 8, &lK[bufi][scD * 8]);  \
    ld_lds16(VTh + (size_t)rvA * 2048 + (kv) + evA * 8, &lV[bufi][scA * 8]);   \
    ld_lds16(VTh + (size_t)rvB * 2048 + (kv) + evB * 8, &lV[bufi][scB * 8]);   \
    ld_lds16(VTh + (size_t)rvC * 2048 + (kv) + evC * 8, &lV[bufi][scC * 8]);   \
    ld_lds16(VTh + (size_t)rvD * 2048 + (kv) + evD * 8, &lV[bufi][scD * 8]);   \
  } while (0)

  float m_run[2] = {-1e30f, -1e30f}, l_run[2] = {0.f, 0.f};
  f32x4 oacc[4][2];
#pragma unroll
  for (int d = 0; d < 4; ++d)
#pragma unroll
    for (int qh = 0; qh < 2; ++qh) oacc[d][qh] = f32x4{0.f, 0.f, 0.f, 0.f};

  STAGE128(0, kvbase);
  __syncthreads();

  for (int s = 0; s < 8; ++s) {
    const int bi = s & 1;
    if (s < 7) STAGE128(bi ^ 1, kvbase + (s + 1) * 128);

    const f16* lKb = lK[bi];
    const f16* lVb = lV[bi];

    // ---- QK^T for BOTH tiles (one 16+16 MFMA cluster) ----
    f32x4 sacc[2][4][2];  // [tloc][m][qh]
#pragma unroll
    for (int tloc = 0; tloc < 2; ++tloc) {
      f16x8 kf[4][2];
#pragma unroll
      for (int m = 0; m < 4; ++m)
#pragma unroll
        for (int kk = 0; kk < 2; ++kk)
          kf[m][kk] = *(const f16x8*)&lKb[(tloc * 64 + m * 16 + lo) * 64 +
                                          (((kk << 2) | hi) ^ sw) * 8];
      __builtin_amdgcn_s_setprio(1);
#pragma unroll
      for (int m = 0; m < 4; ++m)
#pragma unroll
        for (int qh = 0; qh < 2; ++qh) {
          sacc[tloc][m][qh] = f32x4{0.f, 0.f, 0.f, 0.f};
#pragma unroll
          for (int kk = 0; kk < 2; ++kk)
            sacc[tloc][m][qh] =
                MFMA_F16(kf[m][kk], qf[qh][kk], sacc[tloc][m][qh]);
        }
      __builtin_amdgcn_s_setprio(0);
    }

    // ---- per tile: V frags, softmax, PV ----
#pragma unroll
    for (int tloc = 0; tloc < 2; ++tloc) {
      const int kv0 = kvbase + s * 128 + tloc * 64;
      // V frags: one b128 each (pi-permuted layout); 16-chunk row swizzle ^lo
      f16x8 vf[4][2];
#pragma unroll
      for (int d = 0; d < 4; ++d)
#pragma unroll
        for (int kk = 0; kk < 2; ++kk)
          vf[d][kk] = *(const f16x8*)&lVb[(d * 16 + lo) * 128 +
                                          ((tloc * 8 + kk * 4 + hi) ^ lo) * 8];

      const int rmin = kv0 - (qlo + 31);
      const int rmax = kv0 + 63 - qlo;
      const bool far = (rmin >= 91) || (rmax <= -91);
      const float bfar = (rmin >= 91) ? bp : bn;
      const int kvl = kv0 - kvbase;

      f16x8 pf[2][2];
#pragma unroll
      for (int qh = 0; qh < 2; ++qh) {
        const int bofs = qh ? bofs1 : bofs0;
        float p[16];
        float mx = -1e30f;
#pragma unroll
        for (int i = 0; i < 16; ++i) {
          float bia = far ? bfar
                          : biasL[kvl + (i >> 2) * 16 + hi * 4 + (i & 3) + bofs];
          float sval = sacc[tloc][i >> 2][qh][i & 3] + bia;
          p[i] = sval;
          mx = fmaxf(mx, sval);
        }
        mx = fmaxf(mx, __shfl_xor(mx, 16, 64));
        mx = fmaxf(mx, __shfl_xor(mx, 32, 64));
        if (!__all(mx <= m_run[qh] + 11.5416f)) {  // defer-max (e^8 in log2)
          float mn = fmaxf(m_run[qh], mx);
          float sc = exp2f(m_run[qh] - mn);
          l_run[qh] *= sc;
#pragma unroll
          for (int d = 0; d < 4; ++d) oacc[d][qh] *= sc;
          m_run[qh] = mn;
        }
        float ps = 0.f;
#pragma unroll
        for (int i = 0; i < 16; ++i) {
          p[i] = exp2f(p[i] - m_run[qh]);
          ps += p[i];
        }
        ps += __shfl_xor(ps, 16, 64);
        ps += __shfl_xor(ps, 32, 64);
        l_run[qh] += ps;
#pragma unroll
        for (int kk = 0; kk < 2; ++kk)
#pragma unroll
          for (int j = 0; j < 8; ++j)
            pf[qh][kk][j] = (f16)p[(kk * 2 + (j >> 2)) * 4 + (j & 3)];
      }

      __builtin_amdgcn_s_setprio(1);
#pragma unroll
      for (int d = 0; d < 4; ++d)
#pragma unroll
        for (int qh = 0; qh < 2; ++qh)
#pragma unroll
          for (int kk = 0; kk < 2; ++kk)
            oacc[d][qh] = MFMA_F16(vf[d][kk], pf[qh][kk], oacc[d][qh]);
      __builtin_amdgcn_s_setprio(0);
    }

    __syncthreads();
  }
#undef STAGE128

  // ---- epilogue: normalized partial O -> Oh[z], (m,l) -> Ml[z] ----
  f16* OhZ = Oh + (size_t)z * 2048 * 1024;
#pragma unroll
  for (int qh = 0; qh < 2; ++qh) {
    const int myq = qh ? myq1 : myq0;
    float inv = 1.f / l_run[qh];
#pragma unroll
    for (int d = 0; d < 4; ++d) {
      f16x4 ov;
#pragma unroll
      for (int r = 0; r < 4; ++r) ov[r] = (f16)(oacc[d][qh][r] * inv);
      *(f16x4*)(OhZ + (size_t)myq * 1024 + h * 64 + d * 16 + hi * 4) = ov;
    }
    if (hi == 0) Ml[(z * 16 + h) * 2048 + myq] = float2{m_run[qh], l_run[qh]};
  }
}

// ---------------------------------------------------------------------------
// exact merge of the two KV-half partials: AO = w0*Oh0 + w1*Oh1 (exp2 domain)
// ---------------------------------------------------------------------------
__global__ __launch_bounds__(256) void merge_halves(
    const f16* __restrict__ Oh, const float2* __restrict__ Ml,
    f16* __restrict__ AO) {
  int idx = blockIdx.x * 256 + threadIdx.x;  // 262144 f16x8 chunks
  int q = idx >> 7;                          // 128 chunks per q-row
  int h = (idx & 127) >> 3;                  // 8 chunks per head
  float2 ml0 = Ml[h * 2048 + q];
  float2 ml1 = Ml[(16 + h) * 2048 + q];
  float M = fmaxf(ml0.x, ml1.x);
  float w0 = ml0.y * exp2f(ml0.x - M);
  float w1 = ml1.y * exp2f(ml1.x - M);
  float inv = 1.f / (w0 + w1);
  w0 *= inv;
  w1 *= inv;
  f16x8 a = ((const f16x8*)Oh)[idx];
  f16x8 b = ((const f16x8*)(Oh + (size_t)2048 * 1024))[idx];
  f16x8 o;
#pragma unroll
  for (int r = 0; r < 8; ++r)
    o[r] = (f16)(w0 * (float)a[r] + w1 * (float)b[r]);
  ((f16x8*)AO)[idx] = o;
}

// ---------------------------------------------------------------------------
extern "C" void kernel_launch(void* const* d_in, const int* in_sizes, int n_in,
                              void* d_out, int out_size, void* d_ws, size_t ws_size,
                              hipStream_t stream) {
  const float* hs = (const float*)d_in[0];
  const float* wq = (const float*)d_in[1];
  const float* wk = (const float*)d_in[2];
  const float* wv = (const float*)d_in[3];
  const float* wo = (const float*)d_in[4];
  const float* rb = (const float*)d_in[5];

  char* w = (char*)d_ws;
  f16* hb  = (f16*)w; w += (size_t)2048 * 1024 * 2;
  f16* wqb = (f16*)w; w += (size_t)1024 * 1024 * 2;
  f16* wkb = (f16*)w; w += (size_t)1024 * 1024 * 2;
  f16* wvb = (f16*)w; w += (size_t)1024 * 1024 * 2;
  f16* wob = (f16*)w; w += (size_t)1024 * 1024 * 2;
  f16* Qb  = (f16*)w; w += (size_t)2048 * 1024 * 2;
  f16* Kb  = (f16*)w; w += (size_t)2048 * 1024 * 2;
  f16* VTb = (f16*)w; w += (size_t)2048 * 1024 * 2;
  f16* AOb = (f16*)w; w += (size_t)2048 * 1024 * 2;
  float* btab = (float*)w; w += (size_t)16 * 4096 * 4;

  // partial buffers reuse hb/wqb/wkb (8 MB, dead after gemm_qkv) and wvb:
  f16* Oh = hb;                 // [2][2048][1024] f16 = 8 MB
  float2* Ml = (float2*)wvb;    // [2][16][2048] float2 = 512 KB

  cast_all<<<6144, 256, 0, stream>>>(hs, wq, wk, wv, wo, hb, wqb, wkb, wvb, wob);
  build_bias<<<256, 256, 0, stream>>>(rb, btab);
  gemm_qkv<<<dim3(32, 8, 3), 256, 0, stream>>>(hb, wqb, wkb, wvb, Qb, Kb, VTb);
  attn_kernel<<<dim3(16, 16, 2), 256, 0, stream>>>(Qb, Kb, VTb, btab, Oh, Ml);
  merge_halves<<<1024, 256, 0, stream>>>(Oh, Ml, AOb);
  gemm_out<<<dim3(32, 8), 256, 0, stream>>>(AOb, wob, (float*)d_out);
}

// Round 11
// 93.832 us; speedup vs baseline: 1.3040x; 1.3040x over previous
//
#include <hip/hip_runtime.h>
#include <hip/hip_bf16.h>

typedef _Float16 f16;
typedef f16 f16x8 __attribute__((ext_vector_type(8)));
typedef f16 f16x4 __attribute__((ext_vector_type(4)));
typedef float f32x4 __attribute__((ext_vector_type(4)));

#define MFMA_F16(a, b, c) __builtin_amdgcn_mfma_f32_16x16x32_f16((a), (b), (c), 0, 0, 0)
#define LOG2E 1.44269504f

// ---------------------------------------------------------------------------
// async global->LDS 16B copy
// ---------------------------------------------------------------------------
__device__ __forceinline__ void ld_lds16(const void* g, void* l) {
  __builtin_amdgcn_global_load_lds((const __attribute__((address_space(1))) void*)g,
                                   (__attribute__((address_space(3))) void*)l, 16, 0, 0);
}

// ---------------------------------------------------------------------------
// cast fp32 -> fp16; wq scaled by log2(e) (exp2-domain softmax)
// ---------------------------------------------------------------------------
__global__ __launch_bounds__(256) void cast_all(
    const float* __restrict__ hs, const float* __restrict__ wq,
    const float* __restrict__ wk, const float* __restrict__ wv,
    const float* __restrict__ wo, f16* __restrict__ hb,
    f16* __restrict__ wqb, f16* __restrict__ wkb,
    f16* __restrict__ wvb, f16* __restrict__ wob) {
  int idx = blockIdx.x * 256 + threadIdx.x;  // 1,572,864 float4 chunks total
  const float* src;
  f16* dst;
  int j;
  float scale = 1.0f;
  if (idx < 524288) {  // hidden: 2M floats / 4
    src = hs; dst = hb; j = idx;
  } else {
    int t = idx - 524288;
    int w = t >> 18;      // 262144 float4 per weight
    j = t & 262143;
    src = (w == 0) ? wq : (w == 1) ? wk : (w == 2) ? wv : wo;
    dst = (w == 0) ? wqb : (w == 1) ? wkb : (w == 2) ? wvb : wob;
    if (w == 0) scale = LOG2E;
  }
  float4 v = ((const float4*)src)[j];
  f16x4 o;
  o[0] = (f16)(v.x * scale); o[1] = (f16)(v.y * scale);
  o[2] = (f16)(v.z * scale); o[3] = (f16)(v.w * scale);
  ((f16x4*)dst)[j] = o;
}

// ---------------------------------------------------------------------------
// relative-position bias table: btab[h][rel + 2047], rel = kv - q, *log2(e)
// ---------------------------------------------------------------------------
__global__ __launch_bounds__(256) void build_bias(const float* __restrict__ rb,
                                                  float* __restrict__ btab) {
  int idx = blockIdx.x * 256 + threadIdx.x;  // 65536 = 16 heads * 4096
  int h = idx >> 12;
  int t = idx & 4095;
  int rel = t - 2047;
  int bucket = (rel > 0) ? 16 : 0;
  int a = (rel < 0) ? -rel : rel;
  int lg;
  if (a < 8) {
    lg = a;
  } else {
    int cnt = (a >= 12) + (a >= 16) + (a >= 23) + (a >= 32) + (a >= 46) +
              (a >= 64) + (a >= 91);
    lg = 8 + cnt;  // max 15
  }
  bucket += lg;
  btab[idx] = rb[bucket * 16 + h] * LOG2E;  // rel_bias[32][16]
}

// ---------------------------------------------------------------------------
// GEMM mainloop: C[64x128] tile of A[M,1024] * B[N,1024]^T, double-buffered:
// stage(k+64) issued BEFORE compute(k), one barrier per iter.
// ---------------------------------------------------------------------------
__device__ __forceinline__ void gemm_mainloop(const f16* __restrict__ A,
                                              const f16* __restrict__ B,
                                              int brow, int bcol,
                                              f16 (*lA)[64 * 64],
                                              f16 (*lB)[128 * 64],
                                              f32x4 acc[4][2]) {
  const int tid = threadIdx.x;
  const int lane = tid & 63;
  const int wn = tid >> 6;
  const int lo = lane & 15;
  const int hi = lane >> 4;
  const int sw = lo & 7;
  const int sr = tid >> 3;                       // 0..31
  const int se = (((tid & 7) ^ (sr & 7)) << 3);  // swizzled col elem offset
  const f16* gA = A + (size_t)(brow + sr) * 1024 + se;
  const f16* gB = B + (size_t)(bcol + sr) * 1024 + se;

#define GSTAGE(bi, k0_)                                                        \
  do {                                                                         \
    ld_lds16(gA + (k0_),             lA[bi] + tid * 8);                        \
    ld_lds16(gA + (k0_) + 32 * 1024, lA[bi] + tid * 8 + 2048);                 \
    ld_lds16(gB + (k0_),             lB[bi] + tid * 8);                        \
    ld_lds16(gB + (k0_) + 32 * 1024, lB[bi] + tid * 8 + 2048);                 \
    ld_lds16(gB + (k0_) + 64 * 1024, lB[bi] + tid * 8 + 4096);                 \
    ld_lds16(gB + (k0_) + 96 * 1024, lB[bi] + tid * 8 + 6144);                 \
  } while (0)

  GSTAGE(0, 0);
  __syncthreads();
  for (int k0 = 0; k0 < 1024; k0 += 64) {
    const int bi = (k0 >> 6) & 1;
    if (k0 < 960) GSTAGE(bi ^ 1, k0 + 64);
    f16x8 af[4][2], bf[2][2];
#pragma unroll
    for (int m = 0; m < 4; ++m)
#pragma unroll
      for (int ks = 0; ks < 2; ++ks)
        af[m][ks] = *(const f16x8*)(lA[bi] + (m * 16 + lo) * 64 +
                                    (((ks << 2) | hi) ^ sw) * 8);
#pragma unroll
    for (int j = 0; j < 2; ++j)
#pragma unroll
      for (int ks = 0; ks < 2; ++ks)
        bf[j][ks] = *(const f16x8*)(lB[bi] + (wn * 32 + j * 16 + lo) * 64 +
                                    (((ks << 2) | hi) ^ sw) * 8);
    __builtin_amdgcn_s_setprio(1);
#pragma unroll
    for (int m = 0; m < 4; ++m)
#pragma unroll
      for (int j = 0; j < 2; ++j)
#pragma unroll
        for (int ks = 0; ks < 2; ++ks)
          acc[m][j] = MFMA_F16(af[m][ks], bf[j][ks], acc[m][j]);
    __builtin_amdgcn_s_setprio(0);
    __syncthreads();  // stage(bi^1) retired + everyone done reading bi
  }
#undef GSTAGE
}

// QKV projections fused over blockIdx.z (0=Q, 1=K, 2=V-transposed+pi-permuted)
__global__ __launch_bounds__(256) void gemm_qkv(
    const f16* __restrict__ A, const f16* __restrict__ Wq,
    const f16* __restrict__ Wk, const f16* __restrict__ Wv,
    f16* __restrict__ Qo, f16* __restrict__ Ko, f16* __restrict__ VTo) {
  __shared__ __align__(16) f16 lA[2][64 * 64];
  __shared__ __align__(16) f16 lB[2][128 * 64];
  const int z = blockIdx.z;
  const f16* B = (z == 0) ? Wq : (z == 1) ? Wk : Wv;
  const int brow = blockIdx.x * 64, bcol = blockIdx.y * 128;
  f32x4 acc[4][2];
#pragma unroll
  for (int m = 0; m < 4; ++m)
#pragma unroll
    for (int j = 0; j < 2; ++j) acc[m][j] = f32x4{0.f, 0.f, 0.f, 0.f};
  gemm_mainloop(A, B, brow, bcol, lA, lB, acc);
  const int lane = threadIdx.x & 63, wn = threadIdx.x >> 6;
  const int lo = lane & 15, hi = lane >> 4;
  if (z < 2) {
    f16* C = z ? Ko : Qo;
#pragma unroll
    for (int m = 0; m < 4; ++m)
#pragma unroll
      for (int j = 0; j < 2; ++j) {
        int col = bcol + wn * 32 + j * 16 + lo;
        int row0 = brow + m * 16 + hi * 4;
#pragma unroll
        for (int r = 0; r < 4; ++r)
          C[(size_t)(row0 + r) * 1024 + col] = (f16)acc[m][j][r];
      }
  } else {
    // V transposed: VT[n][s'], pi-permuted within each 64-kv block so a PV
    // fragment is one contiguous b128 in LDS.
#pragma unroll
    for (int m = 0; m < 4; ++m)
#pragma unroll
      for (int j = 0; j < 2; ++j) {
        int col = bcol + wn * 32 + j * 16 + lo;   // n
        int g = m * 4 + hi;
        int w = g & 7;
        int gp = (g & 8) | ((w < 4) ? (2 * w) : (2 * (w - 4) + 1));
        int sp = brow + gp * 4;                   // permuted s
        f16x4 v4;
#pragma unroll
        for (int r = 0; r < 4; ++r) v4[r] = (f16)acc[m][j][r];
        *(f16x4*)(VTo + (size_t)col * 2048 + sp) = v4;
      }
  }
}

// output projection: AO[2048,1024] * Wo[1024,1024]^T -> fp32 d_out
__global__ __launch_bounds__(256) void gemm_out(const f16* __restrict__ A,
                                                const f16* __restrict__ W,
                                                float* __restrict__ C) {
  __shared__ __align__(16) f16 lA[2][64 * 64];
  __shared__ __align__(16) f16 lB[2][128 * 64];
  const int brow = blockIdx.x * 64, bcol = blockIdx.y * 128;
  f32x4 acc[4][2];
#pragma unroll
  for (int m = 0; m < 4; ++m)
#pragma unroll
    for (int j = 0; j < 2; ++j) acc[m][j] = f32x4{0.f, 0.f, 0.f, 0.f};
  gemm_mainloop(A, W, brow, bcol, lA, lB, acc);
  const int lane = threadIdx.x & 63, wn = threadIdx.x >> 6;
  const int lo = lane & 15, hi = lane >> 4;
#pragma unroll
  for (int m = 0; m < 4; ++m)
#pragma unroll
    for (int j = 0; j < 2; ++j) {
      int col = bcol + wn * 32 + j * 16 + lo;
      int row0 = brow + m * 16 + hi * 4;
#pragma unroll
      for (int r = 0; r < 4; ++r)
        C[(size_t)(row0 + r) * 1024 + col] = acc[m][j][r];
    }
}

// ---------------------------------------------------------------------------
// Flash attention v11 = best-known consolidation:
// r4/r5 2-deep pipeline (16q/wave, 64-kv tiles, 2x32KB buffers, grid 32x16,
// direct epilogue, no split/merge) + pi-permuted V (one b128/frag) +
// exp2-domain softmax + far-tile scalar bias + setprio + defer-max.
// ---------------------------------------------------------------------------
__global__ __launch_bounds__(256, 2) void attn_kernel(
    const f16* __restrict__ Q, const f16* __restrict__ K,
    const f16* __restrict__ VT, const float* __restrict__ btab,
    f16* __restrict__ AO) {
  __shared__ __align__(16) f16 lK[2][4096];
  __shared__ __align__(16) f16 lV[2][4096];

  const int h = blockIdx.y;
  const int q0 = blockIdx.x * 64;
  const int tid = threadIdx.x;
  const int wave = tid >> 6, lane = tid & 63;
  const int lo = lane & 15, hi = lane >> 4;
  const int sw = lo & 7;
  const int qlo = q0 + wave * 16;
  const int myq = qlo + lo;

  const f16* Kh = K + h * 64;
  const f16* VTh = VT + (size_t)h * 64 * 2048;
  const float* bt = btab + h * 4096 + 2047 - myq;

  // Q fragments (B-operand, cols = q): registers for whole kernel
  f16x8 qf[2];
#pragma unroll
  for (int kk = 0; kk < 2; ++kk)
    qf[kk] = *(const f16x8*)(Q + (size_t)myq * 1024 + h * 64 + kk * 32 + hi * 8);

  // far-tile scalar biases (saturated buckets), log2e-scaled
  const float bp = btab[h * 4096 + 4094];  // rel >= +91 (bucket 31)
  const float bn = btab[h * 4096 + 0];     // rel <= -91 (bucket 15)

  // staging chunk indices (2 chunks each for K and V per thread)
  const int sc0 = wave * 64 + lane;
  const int sc1 = 256 + sc0;
  const int r0 = sc0 >> 3, e0 = (sc0 & 7) ^ (r0 & 7);
  const int r1 = sc1 >> 3, e1 = (sc1 & 7) ^ (r1 & 7);

#define STAGE(bufi, kv)                                                        \
  do {                                                                         \
    ld_lds16(Kh + (size_t)((kv) + r0) * 1024 + e0 * 8, &lK[bufi][sc0 * 8]);    \
    ld_lds16(Kh + (size_t)((kv) + r1) * 1024 + e1 * 8, &lK[bufi][sc1 * 8]);    \
    ld_lds16(VTh + (size_t)r0 * 2048 + (kv) + e0 * 8, &lV[bufi][sc0 * 8]);     \
    ld_lds16(VTh + (size_t)r1 * 2048 + (kv) + e1 * 8, &lV[bufi][sc1 * 8]);     \
  } while (0)

  float m_run = -1e30f, l_run = 0.f;
  f32x4 oacc[4];
#pragma unroll
  for (int d = 0; d < 4; ++d) oacc[d] = f32x4{0.f, 0.f, 0.f, 0.f};

  // two-tile pipeline state
  f16x8 vfA[4][2], vfB[4][2];
  f32x4 saccA[4], saccB[4];
  float biasA[16], biasB[16];

// ds-reads (K frags + V->regs as single b128s), stage next, QK^T into CUR
#define TILE_FRONT(t_, CUR)                                                    \
  {                                                                            \
    const int b_ = (t_) & 1;                                                   \
    const int kv0_ = (t_) * 64;                                                \
    const f16* lKb_ = lK[b_];                                                  \
    const f16* lVb_ = lV[b_];                                                  \
    f16x8 kf_[4][2];                                                           \
    _Pragma("unroll") for (int m_ = 0; m_ < 4; ++m_)                           \
      _Pragma("unroll") for (int kk_ = 0; kk_ < 2; ++kk_)                      \
        kf_[m_][kk_] = *(const f16x8*)&lKb_[(m_ * 16 + lo) * 64 +              \
                                            (((kk_ << 2) | hi) ^ sw) * 8];     \
    _Pragma("unroll") for (int d_ = 0; d_ < 4; ++d_)                           \
      _Pragma("unroll") for (int kk_ = 0; kk_ < 2; ++kk_)                      \
        vf##CUR[d_][kk_] = *(const f16x8*)&lVb_[(d_ * 16 + lo) * 64 +          \
                                                ((kk_ * 4 + hi) ^ sw) * 8];    \
    if ((t_) < 31) STAGE(1 - b_, kv0_ + 64);                                   \
    {                                                                          \
      const int rmin_ = kv0_ - (qlo + 15);                                     \
      const int rmax_ = kv0_ + 63 - qlo;                                       \
      if (rmin_ >= 91 || rmax_ <= -91) {                                       \
        const float bf_ = (rmin_ >= 91) ? bp : bn;                             \
        _Pragma("unroll") for (int i_ = 0; i_ < 16; ++i_) bias##CUR[i_] = bf_; \
      } else {                                                                 \
        _Pragma("unroll") for (int i_ = 0; i_ < 16; ++i_)                      \
          bias##CUR[i_] = bt[kv0_ + (i_ >> 2) * 16 + hi * 4 + (i_ & 3)];       \
      }                                                                        \
    }                                                                          \
    __builtin_amdgcn_s_setprio(1);                                             \
    _Pragma("unroll") for (int m_ = 0; m_ < 4; ++m_) {                         \
      sacc##CUR[m_] = f32x4{0.f, 0.f, 0.f, 0.f};                               \
      _Pragma("unroll") for (int kk_ = 0; kk_ < 2; ++kk_)                      \
        sacc##CUR[m_] = MFMA_F16(kf_[m_][kk_], qf[kk_], sacc##CUR[m_]);        \
    }                                                                          \
    __builtin_amdgcn_s_setprio(0);                                             \
  }

// softmax (exp2 domain) + PV for tile held in PRV state
#define SOFTMAX_PV(PRV)                                                        \
  {                                                                            \
    float p_[16];                                                              \
    float mx_ = -1e30f;                                                        \
    _Pragma("unroll") for (int i_ = 0; i_ < 16; ++i_) {                        \
      float s_ = sacc##PRV[i_ >> 2][i_ & 3] + bias##PRV[i_];                   \
      p_[i_] = s_;                                                             \
      mx_ = fmaxf(mx_, s_);                                                    \
    }                                                                          \
    mx_ = fmaxf(mx_, __shfl_xor(mx_, 16, 64));                                 \
    mx_ = fmaxf(mx_, __shfl_xor(mx_, 32, 64));                                 \
    if (!__all(mx_ <= m_run + 11.5416f)) {                                     \
      float mn_ = fmaxf(m_run, mx_);                                           \
      float sc_ = exp2f(m_run - mn_);                                          \
      l_run *= sc_;                                                            \
      _Pragma("unroll") for (int d_ = 0; d_ < 4; ++d_) oacc[d_] *= sc_;        \
      m_run = mn_;                                                             \
    }                                                                          \
    float ps_ = 0.f;                                                           \
    _Pragma("unroll") for (int i_ = 0; i_ < 16; ++i_) {                        \
      p_[i_] = exp2f(p_[i_] - m_run);                                          \
      ps_ += p_[i_];                                                           \
    }                                                                          \
    ps_ += __shfl_xor(ps_, 16, 64);                                            \
    ps_ += __shfl_xor(ps_, 32, 64);                                            \
    l_run += ps_;                                                              \
    f16x8 pf_[2];                                                              \
    _Pragma("unroll") for (int kk_ = 0; kk_ < 2; ++kk_)                        \
      _Pragma("unroll") for (int j_ = 0; j_ < 8; ++j_)                         \
        pf_[kk_][j_] = (f16)p_[(kk_ * 2 + (j_ >> 2)) * 4 + (j_ & 3)];          \
    __builtin_amdgcn_s_setprio(1);                                             \
    _Pragma("unroll") for (int d_ = 0; d_ < 4; ++d_)                           \
      _Pragma("unroll") for (int kk_ = 0; kk_ < 2; ++kk_)                      \
        oacc[d_] = MFMA_F16(vf##PRV[d_][kk_], pf_[kk_], oacc[d_]);             \
    __builtin_amdgcn_s_setprio(0);                                             \
  }

  STAGE(0, 0);
  __syncthreads();

  TILE_FRONT(0, A);
  __syncthreads();

  for (int k2 = 0; k2 < 15; ++k2) {
    const int t1 = 2 * k2 + 1;
    TILE_FRONT(t1, B);
    SOFTMAX_PV(A);
    __syncthreads();
    TILE_FRONT(t1 + 1, A);
    SOFTMAX_PV(B);
    __syncthreads();
  }
  TILE_FRONT(31, B);
  SOFTMAX_PV(A);
  SOFTMAX_PV(B);

#undef TILE_FRONT
#undef SOFTMAX_PV
#undef STAGE

  // ---- epilogue: O[dv][q] / l -> AO[s][h*64+dv] ----
  float inv = 1.f / l_run;
#pragma unroll
  for (int d = 0; d < 4; ++d) {
    f16x4 ov;
#pragma unroll
    for (int r = 0; r < 4; ++r) ov[r] = (f16)(oacc[d][r] * inv);
    *(f16x4*)(AO + (size_t)myq * 1024 + h * 64 + d * 16 + hi * 4) = ov;
  }
}

// ---------------------------------------------------------------------------
extern "C" void kernel_launch(void* const* d_in, const int* in_sizes, int n_in,
                              void* d_out, int out_size, void* d_ws, size_t ws_size,
                              hipStream_t stream) {
  const float* hs = (const float*)d_in[0];
  const float* wq = (const float*)d_in[1];
  const float* wk = (const float*)d_in[2];
  const float* wv = (const float*)d_in[3];
  const float* wo = (const float*)d_in[4];
  const float* rb = (const float*)d_in[5];

  char* w = (char*)d_ws;
  f16* hb  = (f16*)w; w += (size_t)2048 * 1024 * 2;
  f16* wqb = (f16*)w; w += (size_t)1024 * 1024 * 2;
  f16* wkb = (f16*)w; w += (size_t)1024 * 1024 * 2;
  f16* wvb = (f16*)w; w += (size_t)1024 * 1024 * 2;
  f16* wob = (f16*)w; w += (size_t)1024 * 1024 * 2;
  f16* Qb  = (f16*)w; w += (size_t)2048 * 1024 * 2;
  f16* Kb  = (f16*)w; w += (size_t)2048 * 1024 * 2;
  f16* VTb = (f16*)w; w += (size_t)2048 * 1024 * 2;
  f16* AOb = (f16*)w; w += (size_t)2048 * 1024 * 2;
  float* btab = (float*)w; w += (size_t)16 * 4096 * 4;

  cast_all<<<6144, 256, 0, stream>>>(hs, wq, wk, wv, wo, hb, wqb, wkb, wvb, wob);
  build_bias<<<256, 256, 0, stream>>>(rb, btab);
  gemm_qkv<<<dim3(32, 8, 3), 256, 0, stream>>>(hb, wqb, wkb, wvb, Qb, Kb, VTb);
  attn_kernel<<<dim3(32, 16), 256, 0, stream>>>(Qb, Kb, VTb, btab, AOb);
  gemm_out<<<dim3(32, 8), 256, 0, stream>>>(AOb, wob, (float*)d_out);
}